// Round 3
// baseline (1047.264 us; speedup 1.0000x reference)
//
#include <hip/hip_runtime.h>

#define DD 64
#define ROW 256        // output row stride in floats: D*(L+1)
#define CHUNK 1024     // scan chunk

// ---- fused: copy entity_embed -> out slice 0  AND  count edges per head ----
__global__ void k_copy_count(const float* __restrict__ ent, float* __restrict__ out,
                             const int* __restrict__ heads, int* __restrict__ counts,
                             int n_rows, int nE) {
    int idx = blockIdx.x * blockDim.x + threadIdx.x;
    int total = n_rows * 16;                       // n_rows*16 float4s
    if (idx < total) {
        int n = idx >> 4, q = idx & 15;
        const float4* src = (const float4*)(ent + (long)n * DD);
        float4* dst = (float4*)(out + (long)n * ROW);
        dst[q] = src[q];
    }
    if (idx < nE) {
        atomicAdd(counts + heads[idx], 1);
    }
}

// ---- scan step 1: per-chunk exclusive scan + chunk totals -------------------
__global__ __launch_bounds__(256) void k_scan_chunk(
        const int* __restrict__ counts, int* __restrict__ offs,
        int* __restrict__ partials, int n) {
    __shared__ int lds[256];
    int base = blockIdx.x * CHUNK;
    int t = threadIdx.x;
    int c[4]; int sum = 0;
    #pragma unroll
    for (int j = 0; j < 4; ++j) {
        int i = base + t * 4 + j;
        c[j] = (i < n) ? counts[i] : 0;
        sum += c[j];
    }
    lds[t] = sum; __syncthreads();
    for (int d = 1; d < 256; d <<= 1) {
        int v = (t >= d) ? lds[t - d] : 0;
        __syncthreads();
        lds[t] += v;
        __syncthreads();
    }
    int excl = lds[t] - sum;
    if (t == 255) partials[blockIdx.x] = lds[255];
    int run = excl;
    #pragma unroll
    for (int j = 0; j < 4; ++j) {
        int i = base + t * 4 + j;
        if (i < n) offs[i] = run;
        run += c[j];
    }
}

// ---- scan step 2+3 fused: every block locally scans the (<=128) chunk totals
// in LDS, then adds the chunk offset, writes scatter cursors, finalizes. ------
__global__ __launch_bounds__(256) void k_scan_add(
        int* __restrict__ offs, int* __restrict__ running,
        const int* __restrict__ partials, int n, int nE, int nchunks) {
    __shared__ int lds[128];
    int t = threadIdx.x;
    if (t < 128) {
        int v = (t < nchunks) ? partials[t] : 0;
        lds[t] = v;
    }
    __syncthreads();
    // Hillis-Steele inclusive scan over 128 (2 waves participate)
    for (int d = 1; d < 128; d <<= 1) {
        int u = (t < 128 && t >= d) ? lds[t - d] : 0;
        __syncthreads();
        if (t < 128) lds[t] += u;
        __syncthreads();
    }
    int i = blockIdx.x * 256 + t;
    if (i < n) {
        int ck = i >> 10;
        int excl = (ck == 0) ? 0 : lds[ck - 1];
        int v = offs[i] + excl;
        offs[i] = v;
        running[i] = v;     // scatter cursor init
    } else if (i == n) {
        offs[n] = nE;
    }
}

// ---- scatter edges into CSR order; pack tail | (rel<<20) --------------------
__global__ void k_scatter(const int* __restrict__ heads, const int* __restrict__ rels,
                          const int* __restrict__ tails, int* __restrict__ running,
                          int* __restrict__ packed, int nE) {
    int e = blockIdx.x * 256 + threadIdx.x;
    if (e >= nE) return;
    int h = heads[e];
    int pos = atomicAdd(running + h, 1);
    packed[pos] = tails[e] | (rels[e] << 20);
}

// ---- fused KGAT layer -------------------------------------------------------
// wave per head; 4 edge-groups x 16 lanes, float4 per lane (4 dims).
// Edge descriptors batch-loaded (64/chunk) then distributed via shuffle.
// 2-deep software pipeline, 8 edges per iteration (4 gathers in flight).
// tanh via 2-constant Taylor poly (x + c3 x^3 + c5 x^5, |x|<=0.35; each fma
// reads exactly ONE SGPR constant -> zero VGPR cost). Per-HEAD guard with a
// cold exact-tanh re-walk keeps correctness unconditional.
// __launch_bounds__(256,8) pins VGPR<=64: the 8-waves/SIMD occupancy cliff
// (round 2: 68 VGPR -> 7 waves -> +20us/layer).
__global__ __launch_bounds__(256, 8) void k_layer(
        const int* __restrict__ offs, const int* __restrict__ packed,
        const float* __restrict__ hbase, const float* __restrict__ relemb,
        const float* __restrict__ W, float* __restrict__ outbase,
        int n_heads, int nE) {
    __shared__ float Wt[DD * 65];      // padded transpose: Wt[k*65+j] = W[j][k]
    __shared__ float xs[4][DD];
    for (int idx = threadIdx.x; idx < DD * DD; idx += 256)
        Wt[(idx & 63) * 65 + (idx >> 6)] = W[idx];   // 2-way bank alias: free
    __syncthreads();

    const float c3 = -0.33333334f;     // -1/3
    const float c5 =  0.13333334f;     //  2/15

    int w = threadIdx.x >> 6, lane = threadIdx.x & 63;
    int g = lane >> 4, s = lane & 15;      // group 0..3, sublane 0..15

    for (int hd = blockIdx.x * 4 + w; hd < n_heads; hd += gridDim.x * 4) {
        const float4 eh4 = *(const float4*)(hbase + (long)hd * ROW + 4 * s);
        float4 acc = make_float4(0.f, 0.f, 0.f, 0.f);
        float ssum = 0.f;
        float ax = 0.f;
        int p0 = offs[hd], pe = offs[hd + 1];

        for (int cbase = p0; cbase < pe; cbase += 64) {
            int clen = min(pe - cbase, 64);
            int vAll = packed[min(cbase + lane, nE - 1)];

            // prologue: stages 0 (edges g) and 1 (edges 4+g)
            int i0 = (g < clen) ? g : 0;
            int i1 = (4 + g < clen) ? 4 + g : 0;
            int v0 = __shfl(vAll, i0);
            int v1 = __shfl(vAll, i1);
            float4 tt0 = *(const float4*)(hbase + (long)(v0 & 0xFFFFF) * ROW + 4 * s);
            float4 rr0 = *(const float4*)(relemb + (v0 >> 20) * DD + 4 * s);
            float4 tt1 = *(const float4*)(hbase + (long)(v1 & 0xFFFFF) * ROW + 4 * s);
            float4 rr1 = *(const float4*)(relemb + (v1 >> 20) * DD + 4 * s);

            for (int i = 0; i < clen; i += 8) {
                // prefetch stages for i+8 (clamped; redundant tail hits cache)
                int ia = i + 8 + g;  ia = (ia < clen) ? ia : 0;
                int ib = i + 12 + g; ib = (ib < clen) ? ib : 0;
                int va = __shfl(vAll, ia);
                int vb = __shfl(vAll, ib);
                float4 tta = *(const float4*)(hbase + (long)(va & 0xFFFFF) * ROW + 4 * s);
                float4 rra = *(const float4*)(relemb + (va >> 20) * DD + 4 * s);
                float4 ttb = *(const float4*)(hbase + (long)(vb & 0xFFFFF) * ROW + 4 * s);
                float4 rrb = *(const float4*)(relemb + (vb >> 20) * DD + 4 * s);

                // ---- stage 0: edges i+g ----
                {
                    float sc = 0.f;
                    #pragma unroll
                    for (int q = 0; q < 4; ++q) {
                        float x = (&eh4.x)[q] + (&rr0.x)[q];
                        float z = x * x;
                        float x3 = x * z;
                        float th = fmaf(x3, c3, x);
                        th = fmaf(x3 * z, c5, th);        // tanh(x), |x|<=0.35
                        ax = fmaxf(ax, __builtin_fabsf(x));
                        sc = fmaf((&tt0.x)[q], th, sc);
                    }
                    #pragma unroll
                    for (int off = 1; off <= 8; off <<= 1) sc += __shfl_xor(sc, off);
                    float se = ((i + g) < clen) ? __expf(sc) : 0.f;
                    ssum += se;
                    acc.x = fmaf(se, tt0.x, acc.x);
                    acc.y = fmaf(se, tt0.y, acc.y);
                    acc.z = fmaf(se, tt0.z, acc.z);
                    acc.w = fmaf(se, tt0.w, acc.w);
                }
                // ---- stage 1: edges i+4+g ----
                {
                    float sc = 0.f;
                    #pragma unroll
                    for (int q = 0; q < 4; ++q) {
                        float x = (&eh4.x)[q] + (&rr1.x)[q];
                        float z = x * x;
                        float x3 = x * z;
                        float th = fmaf(x3, c3, x);
                        th = fmaf(x3 * z, c5, th);
                        ax = fmaxf(ax, __builtin_fabsf(x));
                        sc = fmaf((&tt1.x)[q], th, sc);
                    }
                    #pragma unroll
                    for (int off = 1; off <= 8; off <<= 1) sc += __shfl_xor(sc, off);
                    float se = ((i + 4 + g) < clen) ? __expf(sc) : 0.f;
                    ssum += se;
                    acc.x = fmaf(se, tt1.x, acc.x);
                    acc.y = fmaf(se, tt1.y, acc.y);
                    acc.z = fmaf(se, tt1.z, acc.z);
                    acc.w = fmaf(se, tt1.w, acc.w);
                }
                tt0 = tta; rr0 = rra; tt1 = ttb; rr1 = rrb;
            }
        }

        // ---- cold path: poly range exceeded somewhere in this head ->
        // recompute the whole head with exact tanh (correctness fallback;
        // never taken for 0.01-scale embedding data). ----
        if (__any(ax > 0.35f)) {
            acc = make_float4(0.f, 0.f, 0.f, 0.f);
            ssum = 0.f;
            for (int p = p0 + g; p < pe; p += 4) {
                int v = packed[p];
                float4 tt = *(const float4*)(hbase + (long)(v & 0xFFFFF) * ROW + 4 * s);
                float4 rr = *(const float4*)(relemb + (v >> 20) * DD + 4 * s);
                float sc = 0.f;
                #pragma unroll
                for (int q = 0; q < 4; ++q) {
                    float x = (&eh4.x)[q] + (&rr.x)[q];
                    float t = __expf(2.f * x);
                    float th = 1.f - 2.f * __builtin_amdgcn_rcpf(t + 1.f);
                    sc = fmaf((&tt.x)[q], th, sc);
                }
                #pragma unroll
                for (int off = 1; off <= 8; off <<= 1) sc += __shfl_xor(sc, off);
                float se = __expf(sc);
                ssum += se;
                acc.x = fmaf(se, tt.x, acc.x);
                acc.y = fmaf(se, tt.y, acc.y);
                acc.z = fmaf(se, tt.z, acc.z);
                acc.w = fmaf(se, tt.w, acc.w);
            }
        }

        // combine the 4 groups' partial sums (lanes with equal s share dims)
        #pragma unroll
        for (int off = 16; off <= 32; off <<= 1) {
            acc.x += __shfl_xor(acc.x, off);
            acc.y += __shfl_xor(acc.y, off);
            acc.z += __shfl_xor(acc.z, off);
            acc.w += __shfl_xor(acc.w, off);
            ssum  += __shfl_xor(ssum,  off);
        }
        float inv = 1.f / (ssum + 1e-10f);
        float4 x4;
        x4.x = eh4.x + acc.x * inv;  x4.y = eh4.y + acc.y * inv;
        x4.z = eh4.z + acc.z * inv;  x4.w = eh4.w + acc.w * inv;
        if (g == 0) *(float4*)(&xs[w][4 * s]) = x4;   // wave-private slot

        // epilogue: y = leaky_relu(x @ W^T), one output dim per lane
        float y = 0.f;
        const float* xw = xs[w];
        #pragma unroll
        for (int k4 = 0; k4 < DD; k4 += 4) {
            float4 xv = *(const float4*)(xw + k4);
            y += xv.x * Wt[(k4 + 0) * 65 + lane];
            y += xv.y * Wt[(k4 + 1) * 65 + lane];
            y += xv.z * Wt[(k4 + 2) * 65 + lane];
            y += xv.w * Wt[(k4 + 3) * 65 + lane];
        }
        y = y >= 0.f ? y : 0.2f * y;
        outbase[(long)hd * ROW + lane] = y;
    }
}

extern "C" void kernel_launch(void* const* d_in, const int* in_sizes, int n_in,
                              void* d_out, int out_size, void* d_ws, size_t ws_size,
                              hipStream_t stream) {
    const int*   heads = (const int*)d_in[0];
    const int*   rels  = (const int*)d_in[1];
    const int*   tails = (const int*)d_in[2];
    const float* ent   = (const float*)d_in[3];
    const float* rel   = (const float*)d_in[4];
    const float* Ws    = (const float*)d_in[5];
    float* out = (float*)d_out;

    const int nE = in_sizes[0];
    const int N  = in_sizes[3] / DD;
    const int L  = in_sizes[5] / (DD * DD);
    const int NREL = in_sizes[4] / (L * DD);

    int* offs    = (int*)d_ws;           // [N+1]
    int* running = offs + (N + 1);       // [N] (counts, then scatter cursor)
    int* packed  = running + N;          // [E]
    // partials in the TAIL of packed: consumed by scan kernels strictly
    // BEFORE k_scatter writes packed (stream order). 128 slots >= nchunks.
    int* partials = packed + nE - 128;

    dim3 blk(256);
    int nchunks = (N + CHUNK - 1) / CHUNK;   // 98 for N=100000
    int fuse_total = max(N * 16, nE);

    // ---- CSR build (same work every call; no static state) ----
    hipMemsetAsync(running, 0, (size_t)N * sizeof(int), stream);
    k_copy_count<<<(fuse_total + 255) / 256, blk, 0, stream>>>(ent, out, heads, running, N, nE);
    k_scan_chunk<<<nchunks, blk, 0, stream>>>(running, offs, partials, N);
    k_scan_add<<<(N + 1 + 255) / 256, blk, 0, stream>>>(offs, running, partials, N, nE, nchunks);
    k_scatter<<<(nE + 255) / 256, blk, 0, stream>>>(heads, rels, tails, running, packed, nE);

    // ---- layers ----
    for (int l = 0; l < L; ++l) {
        k_layer<<<2048, blk, 0, stream>>>(
            offs, packed, out + l * DD, rel + (long)l * NREL * DD,
            Ws + (long)l * DD * DD, out + (l + 1) * DD, N, nE);
    }
}

// Round 4
// 478.401 us; speedup vs baseline: 2.1891x; 2.1891x over previous
//
#include <hip/hip_runtime.h>

#define DD 64
#define ROW 256        // output row stride in floats: D*(L+1)
#define CHUNK 1024     // scan chunk

// ---- fused: copy entity_embed -> out slice 0  AND  count edges per head ----
__global__ void k_copy_count(const float* __restrict__ ent, float* __restrict__ out,
                             const int* __restrict__ heads, int* __restrict__ counts,
                             int n_rows, int nE) {
    int idx = blockIdx.x * blockDim.x + threadIdx.x;
    int total = n_rows * 16;                       // n_rows*16 float4s
    if (idx < total) {
        int n = idx >> 4, q = idx & 15;
        const float4* src = (const float4*)(ent + (long)n * DD);
        float4* dst = (float4*)(out + (long)n * ROW);
        dst[q] = src[q];
    }
    if (idx < nE) {
        atomicAdd(counts + heads[idx], 1);
    }
}

// ---- scan step 1: per-chunk exclusive scan + chunk totals -------------------
__global__ __launch_bounds__(256) void k_scan_chunk(
        const int* __restrict__ counts, int* __restrict__ offs,
        int* __restrict__ partials, int n) {
    __shared__ int lds[256];
    int base = blockIdx.x * CHUNK;
    int t = threadIdx.x;
    int c[4]; int sum = 0;
    #pragma unroll
    for (int j = 0; j < 4; ++j) {
        int i = base + t * 4 + j;
        c[j] = (i < n) ? counts[i] : 0;
        sum += c[j];
    }
    lds[t] = sum; __syncthreads();
    for (int d = 1; d < 256; d <<= 1) {
        int v = (t >= d) ? lds[t - d] : 0;
        __syncthreads();
        lds[t] += v;
        __syncthreads();
    }
    int excl = lds[t] - sum;
    if (t == 255) partials[blockIdx.x] = lds[255];
    int run = excl;
    #pragma unroll
    for (int j = 0; j < 4; ++j) {
        int i = base + t * 4 + j;
        if (i < n) offs[i] = run;
        run += c[j];
    }
}

// ---- scan step 2+3 fused: every block locally scans the (<=128) chunk totals
// in LDS, then adds the chunk offset, writes scatter cursors, finalizes. ------
__global__ __launch_bounds__(256) void k_scan_add(
        int* __restrict__ offs, int* __restrict__ running,
        const int* __restrict__ partials, int n, int nE, int nchunks) {
    __shared__ int lds[128];
    int t = threadIdx.x;
    if (t < 128) {
        int v = (t < nchunks) ? partials[t] : 0;
        lds[t] = v;
    }
    __syncthreads();
    // Hillis-Steele inclusive scan over 128 (2 waves participate)
    for (int d = 1; d < 128; d <<= 1) {
        int u = (t < 128 && t >= d) ? lds[t - d] : 0;
        __syncthreads();
        if (t < 128) lds[t] += u;
        __syncthreads();
    }
    int i = blockIdx.x * 256 + t;
    if (i < n) {
        int ck = i >> 10;
        int excl = (ck == 0) ? 0 : lds[ck - 1];
        int v = offs[i] + excl;
        offs[i] = v;
        running[i] = v;     // scatter cursor init
    } else if (i == n) {
        offs[n] = nE;
    }
}

// ---- scatter edges into CSR order; pack tail | (rel<<20) --------------------
__global__ void k_scatter(const int* __restrict__ heads, const int* __restrict__ rels,
                          const int* __restrict__ tails, int* __restrict__ running,
                          int* __restrict__ packed, int nE) {
    int e = blockIdx.x * 256 + threadIdx.x;
    if (e >= nE) return;
    int h = heads[e];
    int pos = atomicAdd(running + h, 1);
    packed[pos] = tails[e] | (rels[e] << 20);
}

// ---- fused KGAT layer -------------------------------------------------------
// wave per head; 4 edge-groups x 16 lanes, float4 per lane (4 dims).
// Edge descriptors batch-loaded (64/chunk) then distributed via shuffle.
// 2-deep software pipeline, 8 edges per iteration (4 gathers in flight).
// NOTE (rounds 1-3 evidence): this kernel's natural allocation is 64 VGPR =
// the 8-waves/SIMD cliff. Do NOT add register pressure (poly-tanh guards,
// multi-head epilogues: 68 VGPR -> +20us/layer) and do NOT pin occupancy
// via __launch_bounds__ min-waves (allocator went to 32 VGPR -> scratch
// spills -> 851MB fetch -> +190us/layer). exp-based tanh stays.
__global__ __launch_bounds__(256) void k_layer(
        const int* __restrict__ offs, const int* __restrict__ packed,
        const float* __restrict__ hbase, const float* __restrict__ relemb,
        const float* __restrict__ W, float* __restrict__ outbase,
        int n_heads, int nE) {
    __shared__ float Wt[DD * 65];      // padded transpose: Wt[k*65+j] = W[j][k]
    __shared__ float xs[4][DD];
    for (int idx = threadIdx.x; idx < DD * DD; idx += 256)
        Wt[(idx & 63) * 65 + (idx >> 6)] = W[idx];   // 2-way bank alias: free
    __syncthreads();

    int w = threadIdx.x >> 6, lane = threadIdx.x & 63;
    int g = lane >> 4, s = lane & 15;      // group 0..3, sublane 0..15

    for (int hd = blockIdx.x * 4 + w; hd < n_heads; hd += gridDim.x * 4) {
        const float4 eh4 = *(const float4*)(hbase + (long)hd * ROW + 4 * s);
        float4 acc = make_float4(0.f, 0.f, 0.f, 0.f);
        float ssum = 0.f;
        int p0 = offs[hd], pe = offs[hd + 1];

        for (int cbase = p0; cbase < pe; cbase += 64) {
            int clen = min(pe - cbase, 64);
            int vAll = packed[min(cbase + lane, nE - 1)];

            // prologue: stages 0 (edges g) and 1 (edges 4+g)
            int i0 = (g < clen) ? g : 0;
            int i1 = (4 + g < clen) ? 4 + g : 0;
            int v0 = __shfl(vAll, i0);
            int v1 = __shfl(vAll, i1);
            float4 tt0 = *(const float4*)(hbase + (long)(v0 & 0xFFFFF) * ROW + 4 * s);
            float4 rr0 = *(const float4*)(relemb + (v0 >> 20) * DD + 4 * s);
            float4 tt1 = *(const float4*)(hbase + (long)(v1 & 0xFFFFF) * ROW + 4 * s);
            float4 rr1 = *(const float4*)(relemb + (v1 >> 20) * DD + 4 * s);

            for (int i = 0; i < clen; i += 8) {
                // prefetch stages for i+8 (clamped; redundant tail hits cache)
                int ia = i + 8 + g;  ia = (ia < clen) ? ia : 0;
                int ib = i + 12 + g; ib = (ib < clen) ? ib : 0;
                int va = __shfl(vAll, ia);
                int vb = __shfl(vAll, ib);
                float4 tta = *(const float4*)(hbase + (long)(va & 0xFFFFF) * ROW + 4 * s);
                float4 rra = *(const float4*)(relemb + (va >> 20) * DD + 4 * s);
                float4 ttb = *(const float4*)(hbase + (long)(vb & 0xFFFFF) * ROW + 4 * s);
                float4 rrb = *(const float4*)(relemb + (vb >> 20) * DD + 4 * s);

                // ---- stage 0: edges i+g ----
                {
                    float sc = 0.f;
                    #pragma unroll
                    for (int q = 0; q < 4; ++q) {
                        float xq = (&eh4.x)[q] + (&rr0.x)[q];
                        float t = __expf(2.f * xq);
                        float th = 1.f - 2.f * __builtin_amdgcn_rcpf(t + 1.f);
                        sc += (&tt0.x)[q] * th;
                    }
                    #pragma unroll
                    for (int off = 1; off <= 8; off <<= 1) sc += __shfl_xor(sc, off);
                    float se = ((i + g) < clen) ? __expf(sc) : 0.f;
                    ssum += se;
                    acc.x += se * tt0.x; acc.y += se * tt0.y;
                    acc.z += se * tt0.z; acc.w += se * tt0.w;
                }
                // ---- stage 1: edges i+4+g ----
                {
                    float sc = 0.f;
                    #pragma unroll
                    for (int q = 0; q < 4; ++q) {
                        float xq = (&eh4.x)[q] + (&rr1.x)[q];
                        float t = __expf(2.f * xq);
                        float th = 1.f - 2.f * __builtin_amdgcn_rcpf(t + 1.f);
                        sc += (&tt1.x)[q] * th;
                    }
                    #pragma unroll
                    for (int off = 1; off <= 8; off <<= 1) sc += __shfl_xor(sc, off);
                    float se = ((i + 4 + g) < clen) ? __expf(sc) : 0.f;
                    ssum += se;
                    acc.x += se * tt1.x; acc.y += se * tt1.y;
                    acc.z += se * tt1.z; acc.w += se * tt1.w;
                }
                tt0 = tta; rr0 = rra; tt1 = ttb; rr1 = rrb;
            }
        }

        // combine the 4 groups' partial sums (lanes with equal s share dims)
        #pragma unroll
        for (int off = 16; off <= 32; off <<= 1) {
            acc.x += __shfl_xor(acc.x, off);
            acc.y += __shfl_xor(acc.y, off);
            acc.z += __shfl_xor(acc.z, off);
            acc.w += __shfl_xor(acc.w, off);
            ssum  += __shfl_xor(ssum,  off);
        }
        float inv = 1.f / (ssum + 1e-10f);
        float4 x4;
        x4.x = eh4.x + acc.x * inv;  x4.y = eh4.y + acc.y * inv;
        x4.z = eh4.z + acc.z * inv;  x4.w = eh4.w + acc.w * inv;
        if (g == 0) *(float4*)(&xs[w][4 * s]) = x4;   // wave-private slot

        // epilogue: y = leaky_relu(x @ W^T), one output dim per lane
        float y = 0.f;
        const float* xw = xs[w];
        #pragma unroll
        for (int k4 = 0; k4 < DD; k4 += 4) {
            float4 xv = *(const float4*)(xw + k4);
            y += xv.x * Wt[(k4 + 0) * 65 + lane];
            y += xv.y * Wt[(k4 + 1) * 65 + lane];
            y += xv.z * Wt[(k4 + 2) * 65 + lane];
            y += xv.w * Wt[(k4 + 3) * 65 + lane];
        }
        y = y >= 0.f ? y : 0.2f * y;
        outbase[(long)hd * ROW + lane] = y;
    }
}

extern "C" void kernel_launch(void* const* d_in, const int* in_sizes, int n_in,
                              void* d_out, int out_size, void* d_ws, size_t ws_size,
                              hipStream_t stream) {
    const int*   heads = (const int*)d_in[0];
    const int*   rels  = (const int*)d_in[1];
    const int*   tails = (const int*)d_in[2];
    const float* ent   = (const float*)d_in[3];
    const float* rel   = (const float*)d_in[4];
    const float* Ws    = (const float*)d_in[5];
    float* out = (float*)d_out;

    const int nE = in_sizes[0];
    const int N  = in_sizes[3] / DD;
    const int L  = in_sizes[5] / (DD * DD);
    const int NREL = in_sizes[4] / (L * DD);

    int* offs    = (int*)d_ws;           // [N+1]
    int* running = offs + (N + 1);       // [N] (counts, then scatter cursor)
    int* packed  = running + N;          // [E]
    // partials in the TAIL of packed: consumed by scan kernels strictly
    // BEFORE k_scatter writes packed (stream order). 128 slots >= nchunks.
    int* partials = packed + nE - 128;

    dim3 blk(256);
    int nchunks = (N + CHUNK - 1) / CHUNK;   // 98 for N=100000
    int fuse_total = max(N * 16, nE);

    // ---- CSR build (same work every call; no static state) ----
    hipMemsetAsync(running, 0, (size_t)N * sizeof(int), stream);
    k_copy_count<<<(fuse_total + 255) / 256, blk, 0, stream>>>(ent, out, heads, running, N, nE);
    k_scan_chunk<<<nchunks, blk, 0, stream>>>(running, offs, partials, N);
    k_scan_add<<<(N + 1 + 255) / 256, blk, 0, stream>>>(offs, running, partials, N, nE, nchunks);
    k_scatter<<<(nE + 255) / 256, blk, 0, stream>>>(heads, rels, tails, running, packed, nE);

    // ---- layers ----
    for (int l = 0; l < L; ++l) {
        k_layer<<<2048, blk, 0, stream>>>(
            offs, packed, out + l * DD, rel + (long)l * NREL * DD,
            Ws + (long)l * DD * DD, out + (l + 1) * DD, N, nE);
    }
}